// Round 19
// baseline (158.625 us; speedup 1.0000x reference)
//
#include <hip/hip_runtime.h>
#include <hip/hip_bf16.h>
#include <cstdint>
#include <cstddef>

#define NG 32
#define NP 64
#define ND 512
#define HW 192
#define KS 32  // K=16 slices in pre-tiled layout
#define EPSV 1e-5f

typedef _Float16 half8 __attribute__((ext_vector_type(8)));
typedef float floatx4 __attribute__((ext_vector_type(4)));
typedef float floatx16 __attribute__((ext_vector_type(16)));

// ---- unified pre-pass: src[b][d][x] f32 -> T[b][ks][rb][hi][l31][j] fp16
// (d = ks*16 + hi*8 + j, x = rb*32 + l31).  Fragment-ready AND stage-ready.
__global__ __launch_bounds__(256) void prep_frag(const float* __restrict__ gal,
                                                 const float* __restrict__ prob,
                                                 _Float16* __restrict__ galT4,
                                                 _Float16* __restrict__ probT4) {
  __shared__ float lds[16 * 192];
  const int z = blockIdx.x;   // 0..95: first NP probes, then NG gals
  const int ks = blockIdx.y;  // 0..31
  const float* src;
  _Float16* dst;
  if (z < NP) {
    src = prob + (size_t)z * ND * HW;
    dst = probT4 + (size_t)z * 98304;
  } else {
    src = gal + (size_t)(z - NP) * ND * HW;
    dst = galT4 + (size_t)(z - NP) * 98304;
  }
  src += (size_t)ks * 16 * HW;
  dst += (size_t)ks * 3072;
  const int t = threadIdx.x;
#pragma unroll
  for (int i = 0; i < 12; ++i) lds[i * 256 + t] = src[i * 256 + t];
  __syncthreads();
#pragma unroll
  for (int r = 0; r < 2; ++r) {
    const int h = r * 256 + t;  // h = rb*64 + hi*32 + l31, 384 slots
    if (h < 384) {
      const int rb = h >> 6, hi = (h >> 5) & 1, l31 = h & 31;
      half8 v;
#pragma unroll
      for (int j = 0; j < 8; ++j) v[j] = (_Float16)lds[(hi * 8 + j) * 192 + rb * 32 + l31];
      *(half8*)(dst + (size_t)h * 8) = v;
    }
  }
}

// ---- async 16B global -> LDS
__device__ __forceinline__ void g2l16(const void* g, void* l) {
  __builtin_amdgcn_global_load_lds(
      (const __attribute__((address_space(1))) void*)g,
      (__attribute__((address_space(3))) void*)l, 16, 0, 0);
}

// ---- main fused kernel: one WG (384 thr, 6 waves) per (g,p) pair ----
// Wave grid 3(wy) x 2(wx); wave tile 64y x 96x via 2x3 frags of
// mfma_f32_32x32x16_f16 -> acc 96 AGPR + ~55 VGPR ~= 150 unified regs, under
// the 170 needed for 3 waves/SIMD (__launch_bounds__(384,3)) -> 12 waves/CU,
// +50% TLP vs all prior rounds (the 84us plateau is phase-latency-bound at
// 2 waves/SIMD).  R16's rigid 2-barrier phase, BK=32 triple buffer, counted
// vmcnt(4) keeps stage(kt+2) in flight across barriers.
__global__ __launch_bounds__(384, 3) void qaconv_main(
    const _Float16* __restrict__ galT4, const _Float16* __restrict__ probT4,
    const float* __restrict__ bn_w, const float* __restrict__ bn_b,
    const float* __restrict__ bn_m, const float* __restrict__ bn_v,
    const float* __restrict__ fc_w, const float* __restrict__ fc_b,
    const float* __restrict__ lbn_w, const float* __restrict__ lbn_b,
    const float* __restrict__ lbn_m, const float* __restrict__ lbn_v,
    float* __restrict__ out) {
  __shared__ __align__(16) char tiles[3][24576];  // [buf][A 12KB | B 12KB] = 72KB
  __shared__ float colp[3][HW];
  __shared__ float rowpart[2][HW];
  __shared__ float wsum[6];

  const int bid = blockIdx.x;
  const int g = bid >> 6, p = bid & 63;

  const int t = threadIdx.x;
  const int lane = t & 63, wid = t >> 6;  // wid 0..5
  const int wy = wid % 3;                 // probe-row group (64 rows)
  const int wx = wid / 3;                 // gal-col half (96 cols)
  const int l31 = lane & 31, hi = lane >> 5;

  // staging sources: one BK=32 tile per operand = 6144 halves (12KB) linear;
  // thread t covers A bytes {r*6144 + t*16 | r=0,1} and B likewise.
  const _Float16* pAs = probT4 + (size_t)p * 98304 + (size_t)t * 8;
  const _Float16* pBs = galT4 + (size_t)g * 98304 + (size_t)t * 8;

  floatx16 acc[2][3];
#pragma unroll
  for (int ii = 0; ii < 2; ++ii)
#pragma unroll
    for (int jj = 0; jj < 3; ++jj) acc[ii][jj] = (floatx16)0.f;

  half8 af[2], bf[3];

#define STAGE(kt_, base_)                                            \
  {                                                                  \
    char* db_ = (char*)(base_) + t * 16;                             \
    const _Float16* sa_ = pAs + (size_t)(kt_)*6144;                  \
    const _Float16* sb_ = pBs + (size_t)(kt_)*6144;                  \
    g2l16(sa_, db_);                                                 \
    g2l16(sa_ + 3072, db_ + 6144);                                   \
    g2l16(sb_, db_ + 12288);                                         \
    g2l16(sb_ + 3072, db_ + 18432);                                  \
  }

#define READ5(base_, kc_)                                            \
  {                                                                  \
    const char* bA_ = (const char*)(base_) + (kc_)*6144;             \
    const char* bB_ = (const char*)(base_) + 12288 + (kc_)*6144;     \
    af[0] = *(const half8*)(bA_ + (wy * 2 + 0) * 1024 + lane * 16);  \
    af[1] = *(const half8*)(bA_ + (wy * 2 + 1) * 1024 + lane * 16);  \
    bf[0] = *(const half8*)(bB_ + (wx * 3 + 0) * 1024 + lane * 16);  \
    bf[1] = *(const half8*)(bB_ + (wx * 3 + 1) * 1024 + lane * 16);  \
    bf[2] = *(const half8*)(bB_ + (wx * 3 + 2) * 1024 + lane * 16);  \
  }

#define MFMA6()                                                                  \
  {                                                                              \
    __builtin_amdgcn_s_setprio(1);                                               \
    _Pragma("unroll") for (int ii = 0; ii < 2; ++ii)                             \
        _Pragma("unroll") for (int jj = 0; jj < 3; ++jj)                         \
            acc[ii][jj] = __builtin_amdgcn_mfma_f32_32x32x16_f16(af[ii], bf[jj], \
                                                                 acc[ii][jj], 0, 0, 0); \
    __builtin_amdgcn_s_setprio(0);                                               \
  }

  // SLOT = one kt = two rigid phases (R16 structure).
#define SLOT(kt_, rdb_, stb_, doStage_, vmW_)                \
  {                                                          \
    READ5(rdb_, 0)                                           \
    if (doStage_) STAGE((kt_) + 2, stb_)                     \
    __builtin_amdgcn_sched_barrier(0);                       \
    __builtin_amdgcn_s_barrier();                            \
    asm volatile("s_waitcnt lgkmcnt(0)" ::: "memory");       \
    __builtin_amdgcn_sched_barrier(0);                       \
    MFMA6()                                                  \
    __builtin_amdgcn_s_barrier();                            \
    READ5(rdb_, 1)                                           \
    __builtin_amdgcn_sched_barrier(0);                       \
    asm volatile("s_waitcnt vmcnt(" #vmW_ ")" ::: "memory"); \
    __builtin_amdgcn_s_barrier();                            \
    asm volatile("s_waitcnt lgkmcnt(0)" ::: "memory");       \
    __builtin_amdgcn_sched_barrier(0);                       \
    MFMA6()                                                  \
    __builtin_amdgcn_s_barrier();                            \
  }

  // prologue: stage tiles 0,1 (kt=0 -> buf0, kt=1 -> buf1); stage(0) must land
  STAGE(0, tiles[0])
  STAGE(1, tiles[1])
  asm volatile("s_waitcnt vmcnt(4)" ::: "memory");
  __builtin_amdgcn_s_barrier();

#pragma unroll 1
  for (int m = 0; m < 4; ++m) {  // kt = 0..11
    SLOT(3 * m + 0, tiles[0], tiles[2], true, 4)
    SLOT(3 * m + 1, tiles[1], tiles[0], true, 4)
    SLOT(3 * m + 2, tiles[2], tiles[1], true, 4)
  }
  SLOT(12, tiles[0], tiles[2], true, 4)   // stage(14)->buf2
  SLOT(13, tiles[1], tiles[0], true, 4)   // stage(15)->buf0
  SLOT(14, tiles[2], tiles[1], false, 0)  // drain stage(15)
  // kt = 15 (buf0), final: no stage, no trailing barriers
  READ5(tiles[0], 0)
  asm volatile("s_waitcnt lgkmcnt(0)" ::: "memory");
  __builtin_amdgcn_sched_barrier(0);
  MFMA6()
  READ5(tiles[0], 1)
  asm volatile("s_waitcnt lgkmcnt(0)" ::: "memory");
  __builtin_amdgcn_sched_barrier(0);
  MFMA6()
#undef STAGE
#undef READ5
#undef MFMA6
#undef SLOT

  // ---- epilogue: dual-axis max ----
  // C/D map: col X = wx*96 + fx*32 + l31, row Y = wy*64 + fy*32 + (e&3)+8*(e>>2)+4*hi
#pragma unroll
  for (int fx = 0; fx < 3; ++fx) {
    float v = -3.4e38f;
#pragma unroll
    for (int fy = 0; fy < 2; ++fy)
#pragma unroll
      for (int e = 0; e < 16; ++e) v = fmaxf(v, acc[fy][fx][e]);
    v = fmaxf(v, __shfl_xor(v, 32));
    if (lane < 32) colp[wy][wx * 96 + fx * 32 + lane] = v;
  }
#pragma unroll
  for (int fy = 0; fy < 2; ++fy)
#pragma unroll
    for (int e = 0; e < 16; ++e) {
      float rv = fmaxf(fmaxf(acc[fy][0][e], acc[fy][1][e]), acc[fy][2][e]);
      rv = fmaxf(rv, __shfl_xor(rv, 1));
      rv = fmaxf(rv, __shfl_xor(rv, 2));
      rv = fmaxf(rv, __shfl_xor(rv, 4));
      rv = fmaxf(rv, __shfl_xor(rv, 8));
      rv = fmaxf(rv, __shfl_xor(rv, 16));
      if (l31 == 0) {
        const int Y = wy * 64 + fy * 32 + (e & 3) + 8 * (e >> 2) + 4 * hi;
        rowpart[wx][Y] = rv;
      }
    }
  __syncthreads();

  // ---- fused BN -> fc dot -> logit BN -> sigmoid ----
  float partial = 0.f;
  if (t < HW) {
    const float rmax = fmaxf(rowpart[0][t], rowpart[1][t]);
    const float cmax = fmaxf(fmaxf(colp[0][t], colp[1][t]), colp[2][t]);
    const float scale = bn_w[0] / sqrtf(bn_v[0] + EPSV);
    const float bm = bn_m[0], bb = bn_b[0];
    partial = ((cmax - bm) * scale + bb) * fc_w[t] +
              ((rmax - bm) * scale + bb) * fc_w[HW + t];
  }
#pragma unroll
  for (int off = 1; off < 64; off <<= 1) partial += __shfl_xor(partial, off);
  if (lane == 0) wsum[wid] = partial;
  __syncthreads();
  if (t == 0) {
    float sum = fc_b[0];
#pragma unroll
    for (int w = 0; w < 6; ++w) sum += wsum[w];
    const float logit = (sum - lbn_m[0]) * (lbn_w[0] / sqrtf(lbn_v[0] + EPSV)) + lbn_b[0];
    out[bid] = 1.f / (1.f + expf(-logit * 0.1f));
  }
}

// ---------------- naive f32 fallback (only if ws too small) ----------------
__global__ __launch_bounds__(256) void qaconv_naive(
    const float* __restrict__ gal, const float* __restrict__ prob,
    const float* __restrict__ bn_w, const float* __restrict__ bn_b,
    const float* __restrict__ bn_m, const float* __restrict__ bn_v,
    const float* __restrict__ fc_w, const float* __restrict__ fc_b,
    const float* __restrict__ lbn_w, const float* __restrict__ lbn_b,
    const float* __restrict__ lbn_m, const float* __restrict__ lbn_v,
    float* __restrict__ out) {
  __shared__ float prow[ND];
  __shared__ float rowmaxs[HW];
  __shared__ float colmaxs[HW];
  __shared__ float red[4];
  const int bid = blockIdx.x;
  const int g = bid >> 6, p = bid & 63;
  const int t = threadIdx.x, lane = t & 63, wid = t >> 6;
  const float* gp = gal + (size_t)g * ND * HW;
  const float* pp = prob + (size_t)p * ND * HW;
  float colmax = -3.4e38f;
  for (int y = 0; y < HW; ++y) {
    for (int k = t; k < ND; k += 256) prow[k] = pp[(size_t)k * HW + y];
    __syncthreads();
    float sv = -3.4e38f;
    if (t < HW) {
      sv = 0.f;
      for (int k = 0; k < ND; ++k) sv = fmaf(prow[k], gp[(size_t)k * HW + t], sv);
      colmax = fmaxf(colmax, sv);
    }
    float m = sv;
#pragma unroll
    for (int off = 1; off < 64; off <<= 1) m = fmaxf(m, __shfl_xor(m, off));
    if (lane == 0) red[wid] = m;
    __syncthreads();
    if (t == 0) rowmaxs[y] = fmaxf(fmaxf(red[0], red[1]), fmaxf(red[2], red[3]));
    __syncthreads();
  }
  if (t < HW) colmaxs[t] = colmax;
  __syncthreads();
  float partial = 0.f;
  for (int j = t; j < 2 * HW; j += 256) {
    const float v = (j < HW) ? colmaxs[j] : rowmaxs[j - HW];
    const float sc = (v - bn_m[0]) * (bn_w[0] / sqrtf(bn_v[0] + EPSV)) + bn_b[0];
    partial += sc * fc_w[j];
  }
#pragma unroll
  for (int off = 1; off < 64; off <<= 1) partial += __shfl_xor(partial, off);
  if (lane == 0) red[wid] = partial;
  __syncthreads();
  if (t == 0) {
    const float sum = fc_b[0] + red[0] + red[1] + red[2] + red[3];
    const float logit = (sum - lbn_m[0]) * (lbn_w[0] / sqrtf(lbn_v[0] + EPSV)) + lbn_b[0];
    out[bid] = 1.f / (1.f + expf(-logit * 0.1f));
  }
}

extern "C" void kernel_launch(void* const* d_in, const int* in_sizes, int n_in,
                              void* d_out, int out_size, void* d_ws, size_t ws_size,
                              hipStream_t stream) {
  const float* gal = (const float*)d_in[0];
  const float* prob = (const float*)d_in[1];
  const float* bn_w = (const float*)d_in[2];
  const float* bn_b = (const float*)d_in[3];
  const float* bn_m = (const float*)d_in[4];
  const float* bn_v = (const float*)d_in[5];
  const float* fc_w = (const float*)d_in[6];
  const float* fc_b = (const float*)d_in[7];
  const float* lbn_w = (const float*)d_in[8];
  const float* lbn_b = (const float*)d_in[9];
  const float* lbn_m = (const float*)d_in[10];
  const float* lbn_v = (const float*)d_in[11];
  float* out = (float*)d_out;

  const size_t probT4_elems = (size_t)NP * 98304;  // 6.29M halves
  const size_t galT4_elems = (size_t)NG * 98304;   // 3.15M halves
  const size_t ws_needed = (probT4_elems + galT4_elems) * sizeof(_Float16);
  if (ws_size >= ws_needed) {
    _Float16* probT4 = (_Float16*)d_ws;
    _Float16* galT4 = probT4 + probT4_elems;
    prep_frag<<<dim3(NP + NG, KS), dim3(256), 0, stream>>>(gal, prob, galT4, probT4);
    qaconv_main<<<dim3(NG * NP), dim3(384), 0, stream>>>(
        galT4, probT4, bn_w, bn_b, bn_m, bn_v, fc_w, fc_b, lbn_w, lbn_b, lbn_m, lbn_v, out);
  } else {
    qaconv_naive<<<dim3(NG * NP), dim3(256), 0, stream>>>(
        gal, prob, bn_w, bn_b, bn_m, bn_v, fc_w, fc_b, lbn_w, lbn_b, lbn_m, lbn_v, out);
  }
}

// Round 20
// 115.065 us; speedup vs baseline: 1.3786x; 1.3786x over previous
//
#include <hip/hip_runtime.h>
#include <hip/hip_bf16.h>
#include <cstdint>
#include <cstddef>

#define NG 32
#define NP 64
#define ND 512
#define HW 192
#define KS 32  // K=16 slices in pre-tiled layout
#define EPSV 1e-5f

typedef _Float16 half8 __attribute__((ext_vector_type(8)));
typedef float floatx4 __attribute__((ext_vector_type(4)));
typedef float floatx16 __attribute__((ext_vector_type(16)));

// ---- unified pre-pass: src[b][d][x] f32 -> T[b][ks][rb][hi][l31][j] fp16
// (d = ks*16 + hi*8 + j, x = rb*32 + l31).  Fragment-ready AND stage-ready.
__global__ __launch_bounds__(256) void prep_frag(const float* __restrict__ gal,
                                                 const float* __restrict__ prob,
                                                 _Float16* __restrict__ galT4,
                                                 _Float16* __restrict__ probT4) {
  __shared__ float lds[16 * 192];
  const int z = blockIdx.x;   // 0..95: first NP probes, then NG gals
  const int ks = blockIdx.y;  // 0..31
  const float* src;
  _Float16* dst;
  if (z < NP) {
    src = prob + (size_t)z * ND * HW;
    dst = probT4 + (size_t)z * 98304;
  } else {
    src = gal + (size_t)(z - NP) * ND * HW;
    dst = galT4 + (size_t)(z - NP) * 98304;
  }
  src += (size_t)ks * 16 * HW;
  dst += (size_t)ks * 3072;
  const int t = threadIdx.x;
#pragma unroll
  for (int i = 0; i < 12; ++i) lds[i * 256 + t] = src[i * 256 + t];
  __syncthreads();
#pragma unroll
  for (int r = 0; r < 2; ++r) {
    const int h = r * 256 + t;  // h = rb*64 + hi*32 + l31, 384 slots
    if (h < 384) {
      const int rb = h >> 6, hi = (h >> 5) & 1, l31 = h & 31;
      half8 v;
#pragma unroll
      for (int j = 0; j < 8; ++j) v[j] = (_Float16)lds[(hi * 8 + j) * 192 + rb * 32 + l31];
      *(half8*)(dst + (size_t)h * 8) = v;
    }
  }
}

// ---- async 16B global -> LDS
__device__ __forceinline__ void g2l16(const void* g, void* l) {
  __builtin_amdgcn_global_load_lds(
      (const __attribute__((address_space(1))) void*)g,
      (__attribute__((address_space(3))) void*)l, 16, 0, 0);
}

// ---- main fused kernel: PERSISTENT, 512 blocks (2/CU), 4 pairs each ----
// R16's proven K-loop (96x96 waves, BK=32, triple buffer, rigid 2-barrier
// phase, counted vmcnt) made persistent: each block handles 4 consecutive
// (g,p) pairs SHARING g (B source identical, L2-hot).  Buffer rotation runs
// continuously across pairs (slot s stages s+2, so pair i's slots 14/15 stage
// pair i+1's tiles 0/1) -- the stage pipeline NEVER drains at pair
// boundaries.  Epilogue is barrier-clean (raw s_barrier + lgkmcnt only, no
// __syncthreads vmcnt(0) drain; colp/rowp are separate arrays, no tile
// overlay) so next-pair stages stay in flight through it.
__global__ __launch_bounds__(256, 2) void qaconv_main(
    const _Float16* __restrict__ galT4, const _Float16* __restrict__ probT4,
    const float* __restrict__ bn_w, const float* __restrict__ bn_b,
    const float* __restrict__ bn_m, const float* __restrict__ bn_v,
    const float* __restrict__ fc_w, const float* __restrict__ fc_b,
    const float* __restrict__ lbn_w, const float* __restrict__ lbn_b,
    const float* __restrict__ lbn_m, const float* __restrict__ lbn_v,
    float* __restrict__ out) {
  __shared__ __align__(16) char tiles[3][24576];  // [buf][A 12KB | B 12KB]
  __shared__ float colp[2][HW];
  __shared__ float rowp[2][HW];
  __shared__ float wsum[4];

  const int bid = blockIdx.x;      // 0..511
  const int g = bid >> 4;          // 0..31 (shared by this block's 4 pairs)
  const int p0 = (bid & 15) * 4;   // first probe of the 4

  const int t = threadIdx.x;
  const int lane = t & 63, wid = t >> 6;
  const int wr = wid & 1;   // probe-row half (y block of 96)
  const int wc = wid >> 1;  // gal-col half (x block of 96)
  const int l31 = lane & 31, hi = lane >> 5;

  // uniform scalars once
  const float scale = bn_w[0] / sqrtf(bn_v[0] + EPSV);
  const float bm = bn_m[0], bb = bn_b[0];
  const float lscale = lbn_w[0] / sqrtf(lbn_v[0] + EPSV);
  const float lm = lbn_m[0], lb = lbn_b[0];
  const float fcb = fc_b[0];

  // staging sources (per-lane, linear): B shared across pairs; A per pair
  const _Float16* pB = galT4 + (size_t)g * 98304 + (size_t)t * 8;
  const _Float16* pA0 = probT4 + (size_t)p0 * 98304 + (size_t)t * 8;
  const _Float16* pA1 = pA0 + 98304;
  const _Float16* pA2 = pA1 + 98304;
  const _Float16* pA3 = pA2 + 98304;

  char* const T0 = tiles[0];
  char* const T1 = tiles[1];
  char* const T2 = tiles[2];

  floatx16 acc[3][3];
  half8 raf[3], rbf[3];

#define STAGE(sA_, kt_, base_)                                       \
  {                                                                  \
    char* db_ = (char*)(base_) + t * 16;                             \
    const _Float16* sa_ = (sA_) + (size_t)(kt_)*6144;                \
    const _Float16* sb_ = pB + (size_t)(kt_)*6144;                   \
    g2l16(sa_, db_);                                                 \
    g2l16(sa_ + 2048, db_ + 4096);                                   \
    g2l16(sa_ + 4096, db_ + 8192);                                   \
    g2l16(sb_, db_ + 12288);                                         \
    g2l16(sb_ + 2048, db_ + 16384);                                  \
    g2l16(sb_ + 4096, db_ + 20480);                                  \
  }

#define READ6(base_, kc_)                                            \
  {                                                                  \
    const char* bA_ = (const char*)(base_) + (kc_)*6144;             \
    const char* bB_ = (const char*)(base_) + 12288 + (kc_)*6144;     \
    raf[0] = *(const half8*)(bA_ + (wr * 3 + 0) * 1024 + lane * 16); \
    raf[1] = *(const half8*)(bA_ + (wr * 3 + 1) * 1024 + lane * 16); \
    raf[2] = *(const half8*)(bA_ + (wr * 3 + 2) * 1024 + lane * 16); \
    rbf[0] = *(const half8*)(bB_ + (wc * 3 + 0) * 1024 + lane * 16); \
    rbf[1] = *(const half8*)(bB_ + (wc * 3 + 1) * 1024 + lane * 16); \
    rbf[2] = *(const half8*)(bB_ + (wc * 3 + 2) * 1024 + lane * 16); \
  }

#define MFMA9()                                                                  \
  {                                                                              \
    __builtin_amdgcn_s_setprio(1);                                               \
    _Pragma("unroll") for (int ii = 0; ii < 3; ++ii)                             \
        _Pragma("unroll") for (int jj = 0; jj < 3; ++jj)                         \
            acc[ii][jj] = __builtin_amdgcn_mfma_f32_32x32x16_f16(raf[ii], rbf[jj],\
                                                                 acc[ii][jj], 0, 0, 0); \
    __builtin_amdgcn_s_setprio(0);                                               \
  }

#define SLOT(rdb_, stb_, sA_, skt_, doStage_, vmW_)          \
  {                                                          \
    READ6(rdb_, 0)                                           \
    if (doStage_) STAGE(sA_, skt_, stb_)                     \
    __builtin_amdgcn_sched_barrier(0);                       \
    __builtin_amdgcn_s_barrier();                            \
    asm volatile("s_waitcnt lgkmcnt(0)" ::: "memory");       \
    __builtin_amdgcn_sched_barrier(0);                       \
    MFMA9()                                                  \
    __builtin_amdgcn_s_barrier();                            \
    READ6(rdb_, 1)                                           \
    __builtin_amdgcn_sched_barrier(0);                       \
    asm volatile("s_waitcnt vmcnt(" #vmW_ ")" ::: "memory"); \
    __builtin_amdgcn_s_barrier();                            \
    asm volatile("s_waitcnt lgkmcnt(0)" ::: "memory");       \
    __builtin_amdgcn_sched_barrier(0);                       \
    MFMA9()                                                  \
    __builtin_amdgcn_s_barrier();                            \
  }

#define EPI(pidx_)                                                               \
  {                                                                              \
    _Pragma("unroll") for (int fb = 0; fb < 3; ++fb) {                           \
      float v = -3.4e38f;                                                        \
      _Pragma("unroll") for (int fa = 0; fa < 3; ++fa)                           \
          _Pragma("unroll") for (int e = 0; e < 16; ++e)                         \
              v = fmaxf(v, acc[fa][fb][e]);                                      \
      v = fmaxf(v, __shfl_xor(v, 32));                                           \
      if (lane < 32) colp[wr][wc * 96 + fb * 32 + lane] = v;                     \
    }                                                                            \
    _Pragma("unroll") for (int fa = 0; fa < 3; ++fa)                             \
        _Pragma("unroll") for (int e = 0; e < 16; ++e) {                         \
      float rv = fmaxf(fmaxf(acc[fa][0][e], acc[fa][1][e]), acc[fa][2][e]);      \
      rv = fmaxf(rv, __shfl_xor(rv, 1));                                         \
      rv = fmaxf(rv, __shfl_xor(rv, 2));                                         \
      rv = fmaxf(rv, __shfl_xor(rv, 4));                                         \
      rv = fmaxf(rv, __shfl_xor(rv, 8));                                         \
      rv = fmaxf(rv, __shfl_xor(rv, 16));                                        \
      if (l31 == 0) {                                                            \
        const int Y = wr * 96 + fa * 32 + (e & 3) + 8 * (e >> 2) + 4 * hi;       \
        rowp[wc][Y] = rv;                                                        \
      }                                                                          \
    }                                                                            \
    asm volatile("s_waitcnt lgkmcnt(0)" ::: "memory");                           \
    __builtin_amdgcn_s_barrier();                                                \
    float partial = 0.f;                                                         \
    if (t < HW) {                                                                \
      const float rmax = fmaxf(rowp[0][t], rowp[1][t]);                          \
      const float cmax = fmaxf(colp[0][t], colp[1][t]);                          \
      partial = ((cmax - bm) * scale + bb) * fc_w[t] +                           \
                ((rmax - bm) * scale + bb) * fc_w[HW + t];                       \
    }                                                                            \
    _Pragma("unroll") for (int off = 1; off < 64; off <<= 1)                     \
        partial += __shfl_xor(partial, off);                                     \
    if (lane == 0) wsum[wid] = partial;                                          \
    asm volatile("s_waitcnt lgkmcnt(0)" ::: "memory");                           \
    __builtin_amdgcn_s_barrier();                                                \
    if (t == 0) {                                                                \
      const float sum = fcb + wsum[0] + wsum[1] + wsum[2] + wsum[3];             \
      const float logit = (sum - lm) * lscale + lb;                              \
      out[pidx_] = 1.f / (1.f + expf(-logit * 0.1f));                            \
    }                                                                            \
  }

#define ZACC()                                         \
  _Pragma("unroll") for (int ii = 0; ii < 3; ++ii)     \
      _Pragma("unroll") for (int jj = 0; jj < 3; ++jj) \
          acc[ii][jj] = (floatx16)0.f;

  // Pair body: 16 slots; kt reads buf X[(kt)%3 rotated]; slots 14/15 stage the
  // NEXT pair's tiles 0/1 (continuous rotation: next pair's X0' = this X1).
#define PAIRBODY(X0_, X1_, X2_, curA_, nxtA_, pidx_)   \
  ZACC()                                               \
  _Pragma("unroll 1") for (int m = 0; m < 4; ++m) {    \
    SLOT(X0_, X2_, curA_, 3 * m + 2, 1, 3)             \
    SLOT(X1_, X0_, curA_, 3 * m + 3, 1, 3)             \
    SLOT(X2_, X1_, curA_, 3 * m + 4, 1, 3)             \
  }                                                    \
  SLOT(X0_, X2_, curA_, 14, 1, 3)                      \
  SLOT(X1_, X0_, curA_, 15, 1, 3)                      \
  SLOT(X2_, X1_, nxtA_, 0, 1, 3)                       \
  SLOT(X0_, X2_, nxtA_, 1, 1, 3)                       \
  EPI(pidx_)

#define PAIRLAST(X0_, X1_, X2_, curA_, pidx_)          \
  ZACC()                                               \
  _Pragma("unroll 1") for (int m = 0; m < 4; ++m) {    \
    SLOT(X0_, X2_, curA_, 3 * m + 2, 1, 3)             \
    SLOT(X1_, X0_, curA_, 3 * m + 3, 1, 3)             \
    SLOT(X2_, X1_, curA_, 3 * m + 4, 1, 3)             \
  }                                                    \
  SLOT(X0_, X2_, curA_, 14, 1, 3)                      \
  SLOT(X1_, X0_, curA_, 15, 1, 3)                      \
  SLOT(X2_, X1_, curA_, 0, 0, 0)                       \
  SLOT(X0_, X2_, curA_, 0, 0, 0)                       \
  EPI(pidx_)

  // prologue: stage pair0 tiles 0,1
  STAGE(pA0, 0, T0)
  STAGE(pA0, 1, T1)
  asm volatile("s_waitcnt vmcnt(3)" ::: "memory");
  __builtin_amdgcn_s_barrier();

  const int pidx0 = bid * 4;
  PAIRBODY(T0, T1, T2, pA0, pA1, pidx0 + 0)  // rotation 0: next X0' = T1
  PAIRBODY(T1, T2, T0, pA1, pA2, pidx0 + 1)  // rotation 1
  PAIRBODY(T2, T0, T1, pA2, pA3, pidx0 + 2)  // rotation 2
  PAIRLAST(T0, T1, T2, pA3, pidx0 + 3)       // rotation 0

#undef STAGE
#undef READ6
#undef MFMA9
#undef SLOT
#undef EPI
#undef ZACC
#undef PAIRBODY
#undef PAIRLAST
}

// ---------------- naive f32 fallback (only if ws too small) ----------------
__global__ __launch_bounds__(256) void qaconv_naive(
    const float* __restrict__ gal, const float* __restrict__ prob,
    const float* __restrict__ bn_w, const float* __restrict__ bn_b,
    const float* __restrict__ bn_m, const float* __restrict__ bn_v,
    const float* __restrict__ fc_w, const float* __restrict__ fc_b,
    const float* __restrict__ lbn_w, const float* __restrict__ lbn_b,
    const float* __restrict__ lbn_m, const float* __restrict__ lbn_v,
    float* __restrict__ out) {
  __shared__ float prow[ND];
  __shared__ float rowmaxs[HW];
  __shared__ float colmaxs[HW];
  __shared__ float red[4];
  const int bid = blockIdx.x;
  const int g = bid >> 6, p = bid & 63;
  const int t = threadIdx.x, lane = t & 63, wid = t >> 6;
  const float* gp = gal + (size_t)g * ND * HW;
  const float* pp = prob + (size_t)p * ND * HW;
  float colmax = -3.4e38f;
  for (int y = 0; y < HW; ++y) {
    for (int k = t; k < ND; k += 256) prow[k] = pp[(size_t)k * HW + y];
    __syncthreads();
    float sv = -3.4e38f;
    if (t < HW) {
      sv = 0.f;
      for (int k = 0; k < ND; ++k) sv = fmaf(prow[k], gp[(size_t)k * HW + t], sv);
      colmax = fmaxf(colmax, sv);
    }
    float m = sv;
#pragma unroll
    for (int off = 1; off < 64; off <<= 1) m = fmaxf(m, __shfl_xor(m, off));
    if (lane == 0) red[wid] = m;
    __syncthreads();
    if (t == 0) rowmaxs[y] = fmaxf(fmaxf(red[0], red[1]), fmaxf(red[2], red[3]));
    __syncthreads();
  }
  if (t < HW) colmaxs[t] = colmax;
  __syncthreads();
  float partial = 0.f;
  for (int j = t; j < 2 * HW; j += 256) {
    const float v = (j < HW) ? colmaxs[j] : rowmaxs[j - HW];
    const float sc = (v - bn_m[0]) * (bn_w[0] / sqrtf(bn_v[0] + EPSV)) + bn_b[0];
    partial += sc * fc_w[j];
  }
#pragma unroll
  for (int off = 1; off < 64; off <<= 1) partial += __shfl_xor(partial, off);
  if (lane == 0) red[wid] = partial;
  __syncthreads();
  if (t == 0) {
    const float sum = fc_b[0] + red[0] + red[1] + red[2] + red[3];
    const float logit = (sum - lbn_m[0]) * (lbn_w[0] / sqrtf(lbn_v[0] + EPSV)) + lbn_b[0];
    out[bid] = 1.f / (1.f + expf(-logit * 0.1f));
  }
}

extern "C" void kernel_launch(void* const* d_in, const int* in_sizes, int n_in,
                              void* d_out, int out_size, void* d_ws, size_t ws_size,
                              hipStream_t stream) {
  const float* gal = (const float*)d_in[0];
  const float* prob = (const float*)d_in[1];
  const float* bn_w = (const float*)d_in[2];
  const float* bn_b = (const float*)d_in[3];
  const float* bn_m = (const float*)d_in[4];
  const float* bn_v = (const float*)d_in[5];
  const float* fc_w = (const float*)d_in[6];
  const float* fc_b = (const float*)d_in[7];
  const float* lbn_w = (const float*)d_in[8];
  const float* lbn_b = (const float*)d_in[9];
  const float* lbn_m = (const float*)d_in[10];
  const float* lbn_v = (const float*)d_in[11];
  float* out = (float*)d_out;

  const size_t probT4_elems = (size_t)NP * 98304;  // 6.29M halves
  const size_t galT4_elems = (size_t)NG * 98304;   // 3.15M halves
  const size_t ws_needed = (probT4_elems + galT4_elems) * sizeof(_Float16);
  if (ws_size >= ws_needed) {
    _Float16* probT4 = (_Float16*)d_ws;
    _Float16* galT4 = probT4 + probT4_elems;
    prep_frag<<<dim3(NP + NG, KS), dim3(256), 0, stream>>>(gal, prob, galT4, probT4);
    qaconv_main<<<dim3(512), dim3(256), 0, stream>>>(
        galT4, probT4, bn_w, bn_b, bn_m, bn_v, fc_w, fc_b, lbn_w, lbn_b, lbn_m, lbn_v, out);
  } else {
    qaconv_naive<<<dim3(NG * NP), dim3(256), 0, stream>>>(
        gal, prob, bn_w, bn_b, bn_m, bn_v, fc_w, fc_b, lbn_w, lbn_b, lbn_m, lbn_v, out);
  }
}

// Round 21
// 92.310 us; speedup vs baseline: 1.7184x; 1.2465x over previous
//
#include <hip/hip_runtime.h>
#include <hip/hip_bf16.h>
#include <cstdint>
#include <cstddef>

#define NG 32
#define NP 64
#define ND 512
#define HW 192
#define KS 32  // K=16 slices in pre-tiled layout
#define EPSV 1e-5f

typedef _Float16 half8 __attribute__((ext_vector_type(8)));
typedef float floatx4 __attribute__((ext_vector_type(4)));
typedef float floatx16 __attribute__((ext_vector_type(16)));

// ---- unified pre-pass: src[b][d][x] f32 -> T[b][ks][rb][hi][l31][j] fp16
// (d = ks*16 + hi*8 + j, x = rb*32 + l31).  Fragment-ready AND stage-ready.
__global__ __launch_bounds__(256) void prep_frag(const float* __restrict__ gal,
                                                 const float* __restrict__ prob,
                                                 _Float16* __restrict__ galT4,
                                                 _Float16* __restrict__ probT4) {
  __shared__ float lds[16 * 192];
  const int z = blockIdx.x;   // 0..95: first NP probes, then NG gals
  const int ks = blockIdx.y;  // 0..31
  const float* src;
  _Float16* dst;
  if (z < NP) {
    src = prob + (size_t)z * ND * HW;
    dst = probT4 + (size_t)z * 98304;
  } else {
    src = gal + (size_t)(z - NP) * ND * HW;
    dst = galT4 + (size_t)(z - NP) * 98304;
  }
  src += (size_t)ks * 16 * HW;
  dst += (size_t)ks * 3072;
  const int t = threadIdx.x;
#pragma unroll
  for (int i = 0; i < 12; ++i) lds[i * 256 + t] = src[i * 256 + t];
  __syncthreads();
#pragma unroll
  for (int r = 0; r < 2; ++r) {
    const int h = r * 256 + t;  // h = rb*64 + hi*32 + l31, 384 slots
    if (h < 384) {
      const int rb = h >> 6, hi = (h >> 5) & 1, l31 = h & 31;
      half8 v;
#pragma unroll
      for (int j = 0; j < 8; ++j) v[j] = (_Float16)lds[(hi * 8 + j) * 192 + rb * 32 + l31];
      *(half8*)(dst + (size_t)h * 8) = v;
    }
  }
}

// ---- async 16B global -> LDS
__device__ __forceinline__ void g2l16(const void* g, void* l) {
  __builtin_amdgcn_global_load_lds(
      (const __attribute__((address_space(1))) void*)g,
      (__attribute__((address_space(3))) void*)l, 16, 0, 0);
}

// ---- main fused kernel: one WG (256 thr, 4 waves) per (g,p) pair ----
// R16's rigid 2-barrier phases, but A comes STRAIGHT FROM GLOBAL (frag-ready
// probT4, af-register double-buffered, issued right after each MFMA cluster
// with 2-phase lead) and only B is LDS-staged (BK=32, triple buffer).  LDS
// reads drop 6->3 per phase (reads/MFMA 0.67->0.33) and LDS shrinks to ~52KB
// -> 3 blocks/CU.  The VMEM queue order per kt is fixed:
//   [S(kt+2) x3 | A(2kt+2) x3 | A(2kt+3) x3]
// so a uniform vmcnt(6) at each phase's wait point proves: my A-frags for
// this phase are done, the B-tile staged 2 kt ago is done, and the younger
// stage + A-prefetch (exactly 6 loads) stay in flight across the barrier.
__global__ __launch_bounds__(256, 2) void qaconv_main(
    const _Float16* __restrict__ galT4, const _Float16* __restrict__ probT4,
    const float* __restrict__ bn_w, const float* __restrict__ bn_b,
    const float* __restrict__ bn_m, const float* __restrict__ bn_v,
    const float* __restrict__ fc_w, const float* __restrict__ fc_b,
    const float* __restrict__ lbn_w, const float* __restrict__ lbn_b,
    const float* __restrict__ lbn_m, const float* __restrict__ lbn_v,
    float* __restrict__ out) {
  // tiles: 3 x 12KB (B only) = 36864 B; epilogue overlays rowbuf[192][66] f32
  // (50688 B) on the same storage.  Total LDS ~52KB -> 3 blocks/CU.
  __shared__ __align__(16) char shmem[50688];
  __shared__ float colp[2][HW];
  __shared__ float wsum[4];
  float(*rowbuf)[66] = (float(*)[66])shmem;

  const int bid = blockIdx.x;
  const int g = bid >> 6, p = bid & 63;

  const int t = threadIdx.x;
  const int lane = t & 63, wid = t >> 6;
  const int wr = wid & 1;   // probe-row half (y block of 96)
  const int wc = wid >> 1;  // gal-col half (x block of 96)
  const int l31 = lane & 31, hi = lane >> 5;

  // A source (per-lane, frag-ready): phase f frag i at pAw + f*3072 + i*512
  const _Float16* pAw =
      probT4 + (size_t)p * 98304 + (size_t)(wr * 3) * 512 + (size_t)lane * 8;
  // B stage source (per-lane, linear): kt tile = 6144 halves (12KB)
  const _Float16* pBs = galT4 + (size_t)g * 98304 + (size_t)t * 8;

  char* const T0 = shmem;
  char* const T1 = shmem + 12288;
  char* const T2 = shmem + 24576;

  floatx16 acc[3][3];
#pragma unroll
  for (int ii = 0; ii < 3; ++ii)
#pragma unroll
    for (int jj = 0; jj < 3; ++jj) acc[ii][jj] = (floatx16)0.f;

  half8 af0[3], af1[3], bf[3];

#define STAGE_B(kt_, base_)                                          \
  {                                                                  \
    char* db_ = (char*)(base_) + t * 16;                             \
    const _Float16* sb_ = pBs + (size_t)(kt_)*6144;                  \
    g2l16(sb_, db_);                                                 \
    g2l16(sb_ + 2048, db_ + 4096);                                   \
    g2l16(sb_ + 4096, db_ + 8192);                                   \
  }

#define LOAD_A(AF, f_)                                               \
  {                                                                  \
    const _Float16* a_ = pAw + (size_t)(f_)*3072;                    \
    AF[0] = *(const half8*)(a_);                                     \
    AF[1] = *(const half8*)(a_ + 512);                               \
    AF[2] = *(const half8*)(a_ + 1024);                              \
  }

#define READ_B(base_, kc_)                                           \
  {                                                                  \
    const char* bB_ = (const char*)(base_) + (kc_)*6144;             \
    bf[0] = *(const half8*)(bB_ + (wc * 3 + 0) * 1024 + lane * 16);  \
    bf[1] = *(const half8*)(bB_ + (wc * 3 + 1) * 1024 + lane * 16);  \
    bf[2] = *(const half8*)(bB_ + (wc * 3 + 2) * 1024 + lane * 16);  \
  }

#define MFMA9(AF)                                                                \
  {                                                                              \
    __builtin_amdgcn_s_setprio(1);                                               \
    _Pragma("unroll") for (int ii = 0; ii < 3; ++ii)                             \
        _Pragma("unroll") for (int jj = 0; jj < 3; ++jj)                         \
            acc[ii][jj] = __builtin_amdgcn_mfma_f32_32x32x16_f16(AF[ii], bf[jj], \
                                                                 acc[ii][jj], 0, 0, 0); \
    __builtin_amdgcn_s_setprio(0);                                               \
  }

  // SLOT = one kt = two rigid phases; A-prefetch issues AFTER each MFMA
  // cluster (keeps queue order [S | A | A] and resolves the af WAR cleanly).
#define SLOT(kt_, rdb_, stb_, doStage_, doL0_, doL1_, vw0_, vw1_)    \
  {                                                                  \
    READ_B(rdb_, 0)                                                  \
    if (doStage_) STAGE_B((kt_) + 2, stb_)                           \
    __builtin_amdgcn_sched_barrier(0);                               \
    __builtin_amdgcn_s_barrier();                                    \
    asm volatile("s_waitcnt vmcnt(" #vw0_ ") lgkmcnt(0)" ::: "memory"); \
    __builtin_amdgcn_sched_barrier(0);                               \
    MFMA9(af0)                                                       \
    if (doL0_) LOAD_A(af0, 2 * (kt_) + 2)                            \
    __builtin_amdgcn_sched_barrier(0);                               \
    __builtin_amdgcn_s_barrier();                                    \
    READ_B(rdb_, 1)                                                  \
    __builtin_amdgcn_sched_barrier(0);                               \
    __builtin_amdgcn_s_barrier();                                    \
    asm volatile("s_waitcnt vmcnt(" #vw1_ ") lgkmcnt(0)" ::: "memory"); \
    __builtin_amdgcn_sched_barrier(0);                               \
    MFMA9(af1)                                                       \
    if (doL1_) LOAD_A(af1, 2 * (kt_) + 3)                            \
    __builtin_amdgcn_sched_barrier(0);                               \
    __builtin_amdgcn_s_barrier();                                    \
  }

  // prologue: stage B(0),B(1); load A(0),A(1); ensure S(0) landed block-wide.
  STAGE_B(0, T0)
  STAGE_B(1, T1)
  LOAD_A(af0, 0)
  LOAD_A(af1, 1)
  asm volatile("s_waitcnt vmcnt(9)" ::: "memory");  // S(0) done; S1,A0,A1 in flight
  __builtin_amdgcn_s_barrier();

#pragma unroll 1
  for (int m = 0; m < 4; ++m) {  // kt = 0..11
    SLOT(3 * m + 0, T0, T2, 1, 1, 1, 6, 6)
    SLOT(3 * m + 1, T1, T0, 1, 1, 1, 6, 6)
    SLOT(3 * m + 2, T2, T1, 1, 1, 1, 6, 6)
  }
  SLOT(12, T0, T2, 1, 1, 1, 6, 6)  // stage S(14)->T2
  SLOT(13, T1, T0, 1, 1, 1, 6, 6)  // stage S(15)->T0
  SLOT(14, T2, T1, 0, 1, 1, 3, 3)  // loads A(30),A(31); no S(16)
  SLOT(15, T0, T1, 0, 0, 0, 3, 0)  // final; vmcnt(0) drains A(31)
#undef STAGE_B
#undef LOAD_A
#undef READ_B
#undef MFMA9
#undef SLOT

  // ---- epilogue: dual-axis max ----
  // C/D map: col X = wc*96 + fb*32 + l31, row Y = wr*96 + fa*32 + (e&3)+8*(e>>2)+4*hi
#pragma unroll
  for (int fb = 0; fb < 3; ++fb) {
    float v = -3.4e38f;
#pragma unroll
    for (int fa = 0; fa < 3; ++fa)
#pragma unroll
      for (int e = 0; e < 16; ++e) v = fmaxf(v, acc[fa][fb][e]);
    v = fmaxf(v, __shfl_xor(v, 32));
    if (lane < 32) colp[wr][wc * 96 + fb * 32 + lane] = v;
  }
  __syncthreads();  // all waves done with B tiles -> safe to overlay rowbuf
  // rowmax partials -> rowbuf (overlays tile storage)
#pragma unroll
  for (int fa = 0; fa < 3; ++fa)
#pragma unroll
    for (int e = 0; e < 16; ++e) {
      float rv = acc[fa][0][e];
      rv = fmaxf(rv, acc[fa][1][e]);
      rv = fmaxf(rv, acc[fa][2][e]);
      const int Y = wr * 96 + fa * 32 + (e & 3) + 8 * (e >> 2) + 4 * hi;
      rowbuf[Y][wc * 32 + l31] = rv;
    }
  __syncthreads();

  // ---- fused BN -> fc dot -> logit BN -> sigmoid ----
  float partial = 0.f;
  if (t < HW) {
    const float* rb = rowbuf[t];
    float rmax = -3.4e38f;
#pragma unroll
    for (int j = 0; j < 16; ++j) {
      const floatx4 v = *(const floatx4*)&rb[j * 4];
      rmax = fmaxf(rmax, fmaxf(fmaxf(v[0], v[1]), fmaxf(v[2], v[3])));
    }
    const float cmax = fmaxf(colp[0][t], colp[1][t]);
    const float scale = bn_w[0] / sqrtf(bn_v[0] + EPSV);
    const float bm = bn_m[0], bb = bn_b[0];
    partial = ((cmax - bm) * scale + bb) * fc_w[t] +
              ((rmax - bm) * scale + bb) * fc_w[HW + t];
  }
#pragma unroll
  for (int off = 1; off < 64; off <<= 1) partial += __shfl_xor(partial, off);
  if (lane == 0) wsum[wid] = partial;
  __syncthreads();
  if (t == 0) {
    const float sum = fc_b[0] + wsum[0] + wsum[1] + wsum[2] + wsum[3];
    const float logit = (sum - lbn_m[0]) * (lbn_w[0] / sqrtf(lbn_v[0] + EPSV)) + lbn_b[0];
    out[bid] = 1.f / (1.f + expf(-logit * 0.1f));
  }
}

// ---------------- naive f32 fallback (only if ws too small) ----------------
__global__ __launch_bounds__(256) void qaconv_naive(
    const float* __restrict__ gal, const float* __restrict__ prob,
    const float* __restrict__ bn_w, const float* __restrict__ bn_b,
    const float* __restrict__ bn_m, const float* __restrict__ bn_v,
    const float* __restrict__ fc_w, const float* __restrict__ fc_b,
    const float* __restrict__ lbn_w, const float* __restrict__ lbn_b,
    const float* __restrict__ lbn_m, const float* __restrict__ lbn_v,
    float* __restrict__ out) {
  __shared__ float prow[ND];
  __shared__ float rowmaxs[HW];
  __shared__ float colmaxs[HW];
  __shared__ float red[4];
  const int bid = blockIdx.x;
  const int g = bid >> 6, p = bid & 63;
  const int t = threadIdx.x, lane = t & 63, wid = t >> 6;
  const float* gp = gal + (size_t)g * ND * HW;
  const float* pp = prob + (size_t)p * ND * HW;
  float colmax = -3.4e38f;
  for (int y = 0; y < HW; ++y) {
    for (int k = t; k < ND; k += 256) prow[k] = pp[(size_t)k * HW + y];
    __syncthreads();
    float sv = -3.4e38f;
    if (t < HW) {
      sv = 0.f;
      for (int k = 0; k < ND; ++k) sv = fmaf(prow[k], gp[(size_t)k * HW + t], sv);
      colmax = fmaxf(colmax, sv);
    }
    float m = sv;
#pragma unroll
    for (int off = 1; off < 64; off <<= 1) m = fmaxf(m, __shfl_xor(m, off));
    if (lane == 0) red[wid] = m;
    __syncthreads();
    if (t == 0) rowmaxs[y] = fmaxf(fmaxf(red[0], red[1]), fmaxf(red[2], red[3]));
    __syncthreads();
  }
  if (t < HW) colmaxs[t] = colmax;
  __syncthreads();
  float partial = 0.f;
  for (int j = t; j < 2 * HW; j += 256) {
    const float v = (j < HW) ? colmaxs[j] : rowmaxs[j - HW];
    const float sc = (v - bn_m[0]) * (bn_w[0] / sqrtf(bn_v[0] + EPSV)) + bn_b[0];
    partial += sc * fc_w[j];
  }
#pragma unroll
  for (int off = 1; off < 64; off <<= 1) partial += __shfl_xor(partial, off);
  if (lane == 0) red[wid] = partial;
  __syncthreads();
  if (t == 0) {
    const float sum = fc_b[0] + red[0] + red[1] + red[2] + red[3];
    const float logit = (sum - lbn_m[0]) * (lbn_w[0] / sqrtf(lbn_v[0] + EPSV)) + lbn_b[0];
    out[bid] = 1.f / (1.f + expf(-logit * 0.1f));
  }
}

extern "C" void kernel_launch(void* const* d_in, const int* in_sizes, int n_in,
                              void* d_out, int out_size, void* d_ws, size_t ws_size,
                              hipStream_t stream) {
  const float* gal = (const float*)d_in[0];
  const float* prob = (const float*)d_in[1];
  const float* bn_w = (const float*)d_in[2];
  const float* bn_b = (const float*)d_in[3];
  const float* bn_m = (const float*)d_in[4];
  const float* bn_v = (const float*)d_in[5];
  const float* fc_w = (const float*)d_in[6];
  const float* fc_b = (const float*)d_in[7];
  const float* lbn_w = (const float*)d_in[8];
  const float* lbn_b = (const float*)d_in[9];
  const float* lbn_m = (const float*)d_in[10];
  const float* lbn_v = (const float*)d_in[11];
  float* out = (float*)d_out;

  const size_t probT4_elems = (size_t)NP * 98304;  // 6.29M halves
  const size_t galT4_elems = (size_t)NG * 98304;   // 3.15M halves
  const size_t ws_needed = (probT4_elems + galT4_elems) * sizeof(_Float16);
  if (ws_size >= ws_needed) {
    _Float16* probT4 = (_Float16*)d_ws;
    _Float16* galT4 = probT4 + probT4_elems;
    prep_frag<<<dim3(NP + NG, KS), dim3(256), 0, stream>>>(gal, prob, galT4, probT4);
    qaconv_main<<<dim3(NG * NP), dim3(256), 0, stream>>>(
        galT4, probT4, bn_w, bn_b, bn_m, bn_v, fc_w, fc_b, lbn_w, lbn_b, lbn_m, lbn_v, out);
  } else {
    qaconv_naive<<<dim3(NG * NP), dim3(256), 0, stream>>>(
        gal, prob, bn_w, bn_b, bn_m, bn_v, fc_w, fc_b, lbn_w, lbn_b, lbn_m, lbn_v, out);
  }
}

// Round 22
// 89.727 us; speedup vs baseline: 1.7679x; 1.0288x over previous
//
#include <hip/hip_runtime.h>
#include <hip/hip_bf16.h>
#include <cstdint>
#include <cstddef>

#define NG 32
#define NP 64
#define ND 512
#define HW 192
#define KS 32  // number of K=16 slices in pre-tiled layout
#define EPSV 1e-5f

typedef _Float16 half8 __attribute__((ext_vector_type(8)));
typedef float floatx4 __attribute__((ext_vector_type(4)));
typedef float floatx16 __attribute__((ext_vector_type(16)));

// ---- unified pre-pass: src[b][d][x] f32 -> T[b][ks][rb][hi][l31][j] fp16
// (d = ks*16 + hi*8 + j, x = rb*32 + l31).  Fragment-ready AND stage-ready.
__global__ __launch_bounds__(256) void prep_frag(const float* __restrict__ gal,
                                                 const float* __restrict__ prob,
                                                 _Float16* __restrict__ galT4,
                                                 _Float16* __restrict__ probT4) {
  __shared__ float lds[16 * 192];
  const int z = blockIdx.x;   // 0..95: first NP probes, then NG gals
  const int ks = blockIdx.y;  // 0..31
  const float* src;
  _Float16* dst;
  if (z < NP) {
    src = prob + (size_t)z * ND * HW;
    dst = probT4 + (size_t)z * 98304;
  } else {
    src = gal + (size_t)(z - NP) * ND * HW;
    dst = galT4 + (size_t)(z - NP) * 98304;
  }
  src += (size_t)ks * 16 * HW;
  dst += (size_t)ks * 3072;
  const int t = threadIdx.x;
#pragma unroll
  for (int i = 0; i < 12; ++i) lds[i * 256 + t] = src[i * 256 + t];
  __syncthreads();
#pragma unroll
  for (int r = 0; r < 2; ++r) {
    const int h = r * 256 + t;  // h = rb*64 + hi*32 + l31, 384 slots
    if (h < 384) {
      const int rb = h >> 6, hi = (h >> 5) & 1, l31 = h & 31;
      half8 v;
#pragma unroll
      for (int j = 0; j < 8; ++j) v[j] = (_Float16)lds[(hi * 8 + j) * 192 + rb * 32 + l31];
      *(half8*)(dst + (size_t)h * 8) = v;
    }
  }
}

// ---- async 16B global -> LDS
__device__ __forceinline__ void g2l16(const void* g, void* l) {
  __builtin_amdgcn_global_load_lds(
      (const __attribute__((address_space(1))) void*)g,
      (__attribute__((address_space(3))) void*)l, 16, 0, 0);
}

// ---- main fused kernel: one WG (256 thr, 4 waves) per (g,p) pair ----
// m201-style phase discipline on the BK=32 triple-buffer frame, stage lead 2.
// Each kc is a phase: {READ6 (ds_read before barrier) -> STAGE -> s_barrier ->
// lgkmcnt(0) -> 9 MFMA (setprio) -> s_barrier}.  vmcnt(6) once per kt keeps
// stage(kt+2) in flight across barriers.  Measured best of 21 structural
// variants: 84.1us main, MfmaUtil 41.9%, 0 bank conflicts (R16 anchor).
// Structural limit note: acc 3x3 = 144 AGPR pins 2 waves/SIMD; all smaller-acc
// geometries hit register cliffs (R10/R18/R19) or LDS-ratio walls (R3/R14).
__global__ __launch_bounds__(256, 2) void qaconv_main(
    const _Float16* __restrict__ galT4, const _Float16* __restrict__ probT4,
    const float* __restrict__ bn_w, const float* __restrict__ bn_b,
    const float* __restrict__ bn_m, const float* __restrict__ bn_v,
    const float* __restrict__ fc_w, const float* __restrict__ fc_b,
    const float* __restrict__ lbn_w, const float* __restrict__ lbn_b,
    const float* __restrict__ lbn_m, const float* __restrict__ lbn_v,
    float* __restrict__ out) {
  // K-loop: 3 buffers x [A 12KB | B 12KB] = 73728 B; epilogue overlays
  // rowbuf[192][66] f32 (50688 B) on the same storage.
  __shared__ __align__(16) char shmem[73728];
  __shared__ float colp[2][HW];
  __shared__ float wsum[4];
  float(*rowbuf)[66] = (float(*)[66])shmem;

  const int bid = blockIdx.x;
  const int g = bid >> 6, p = bid & 63;

  const int t = threadIdx.x;
  const int lane = t & 63, wid = t >> 6;
  const int wr = wid & 1;   // probe-row half (y block of 96)
  const int wc = wid >> 1;  // gal-col half (x block of 96)
  const int l31 = lane & 31, hi = lane >> 5;

  // staging sources (per-lane): one BK=32 tile = 12KB linear per operand.
  const _Float16* pAl = probT4 + (size_t)p * 98304 + wid * 512 + lane * 8;
  const _Float16* pBl = galT4 + (size_t)g * 98304 + wid * 512 + lane * 8;
  const int sdst = wid * 1024;  // wave-uniform LDS dest base (+ lane*16 by HW)

  char* const b0 = shmem;
  char* const b1 = shmem + 24576;
  char* const b2 = shmem + 49152;

  floatx16 acc[3][3];
#pragma unroll
  for (int ii = 0; ii < 3; ++ii)
#pragma unroll
    for (int jj = 0; jj < 3; ++jj) acc[ii][jj] = (floatx16)0.f;

  half8 raf[3], rbf[3];

#define STAGE(kt_, base_)                                            \
  {                                                                  \
    char* db_ = (base_) + sdst;                                      \
    const _Float16* sa_ = pAl + (size_t)(kt_)*6144;                  \
    const _Float16* sb_ = pBl + (size_t)(kt_)*6144;                  \
    g2l16(sa_, db_);                                                 \
    g2l16(sa_ + 2048, db_ + 4096);                                   \
    g2l16(sa_ + 4096, db_ + 8192);                                   \
    g2l16(sb_, db_ + 12288);                                         \
    g2l16(sb_ + 2048, db_ + 16384);                                  \
    g2l16(sb_ + 4096, db_ + 20480);                                  \
  }

#define READ6(base_, kc_)                                            \
  {                                                                  \
    const char* bA_ = (base_) + (kc_)*6144;                          \
    const char* bB_ = (base_) + 12288 + (kc_)*6144;                  \
    raf[0] = *(const half8*)(bA_ + (wr * 3 + 0) * 1024 + lane * 16); \
    raf[1] = *(const half8*)(bA_ + (wr * 3 + 1) * 1024 + lane * 16); \
    raf[2] = *(const half8*)(bA_ + (wr * 3 + 2) * 1024 + lane * 16); \
    rbf[0] = *(const half8*)(bB_ + (wc * 3 + 0) * 1024 + lane * 16); \
    rbf[1] = *(const half8*)(bB_ + (wc * 3 + 1) * 1024 + lane * 16); \
    rbf[2] = *(const half8*)(bB_ + (wc * 3 + 2) * 1024 + lane * 16); \
  }

#define MFMA9()                                                                  \
  {                                                                              \
    __builtin_amdgcn_s_setprio(1);                                               \
    _Pragma("unroll") for (int ii = 0; ii < 3; ++ii)                             \
        _Pragma("unroll") for (int jj = 0; jj < 3; ++jj)                         \
            acc[ii][jj] = __builtin_amdgcn_mfma_f32_32x32x16_f16(raf[ii], rbf[jj],\
                                                                 acc[ii][jj], 0, 0, 0); \
    __builtin_amdgcn_s_setprio(0);                                               \
  }

  // SLOT: one kt = two phases.  vmW_ is the phase-1 vmcnt immediate (token).
#define SLOT(kt_, rdb_, stb_, doStage_, vmW_)                        \
  {                                                                  \
    /* phase 0 */                                                    \
    READ6(rdb_, 0)                                                   \
    if (doStage_) STAGE((kt_) + 2, stb_)                             \
    __builtin_amdgcn_sched_barrier(0);                               \
    __builtin_amdgcn_s_barrier();                                    \
    asm volatile("s_waitcnt lgkmcnt(0)" ::: "memory");               \
    __builtin_amdgcn_sched_barrier(0);                               \
    MFMA9()                                                          \
    __builtin_amdgcn_s_barrier();                                    \
    /* phase 1 */                                                    \
    READ6(rdb_, 1)                                                   \
    __builtin_amdgcn_sched_barrier(0);                               \
    asm volatile("s_waitcnt vmcnt(" #vmW_ ")" ::: "memory");         \
    __builtin_amdgcn_s_barrier();                                    \
    asm volatile("s_waitcnt lgkmcnt(0)" ::: "memory");               \
    __builtin_amdgcn_sched_barrier(0);                               \
    MFMA9()                                                          \
    __builtin_amdgcn_s_barrier();                                    \
  }

  // prologue: stage tiles 0,1; ensure stage(0) complete before kt0 reads
  STAGE(0, b0)
  STAGE(1, b1)
  asm volatile("s_waitcnt vmcnt(6)" ::: "memory");
  __builtin_amdgcn_s_barrier();

#pragma unroll 1
  for (int m = 0; m < 4; ++m) {  // kt = 0..11
    SLOT(3 * m + 0, b0, b2, true, 6)
    SLOT(3 * m + 1, b1, b0, true, 6)
    SLOT(3 * m + 2, b2, b1, true, 6)
  }
  SLOT(12, b0, b2, true, 6)
  SLOT(13, b1, b0, true, 6)   // stage(15) -> b0
  SLOT(14, b2, b1, false, 0)  // no stage(16); vmcnt(0) drains stage(15)
  SLOT(15, b0, b1, false, 0)
#undef STAGE
#undef READ6
#undef MFMA9
#undef SLOT

  // ---- epilogue: dual-axis max ----
  // C/D map: col X = wc*96 + fb*32 + l31, row Y = wr*96 + fa*32 + (e&3)+8*(e>>2)+4*hi
#pragma unroll
  for (int fb = 0; fb < 3; ++fb) {
    float v = -3.4e38f;
#pragma unroll
    for (int fa = 0; fa < 3; ++fa)
#pragma unroll
      for (int e = 0; e < 16; ++e) v = fmaxf(v, acc[fa][fb][e]);
    v = fmaxf(v, __shfl_xor(v, 32));
    if (lane < 32) colp[wr][wc * 96 + fb * 32 + lane] = v;
  }
  __syncthreads();  // all waves done with LDS tiles -> safe to overlay rowbuf
  // rowmax partials -> rowbuf (overlays tile storage)
#pragma unroll
  for (int fa = 0; fa < 3; ++fa)
#pragma unroll
    for (int e = 0; e < 16; ++e) {
      float rv = acc[fa][0][e];
      rv = fmaxf(rv, acc[fa][1][e]);
      rv = fmaxf(rv, acc[fa][2][e]);
      const int Y = wr * 96 + fa * 32 + (e & 3) + 8 * (e >> 2) + 4 * hi;
      rowbuf[Y][wc * 32 + l31] = rv;
    }
  __syncthreads();

  // ---- fused BN -> fc dot -> logit BN -> sigmoid ----
  float partial = 0.f;
  if (t < HW) {
    const float* rb = rowbuf[t];
    float rmax = -3.4e38f;
#pragma unroll
    for (int j = 0; j < 16; ++j) {
      const floatx4 v = *(const floatx4*)&rb[j * 4];
      rmax = fmaxf(rmax, fmaxf(fmaxf(v[0], v[1]), fmaxf(v[2], v[3])));
    }
    const float cmax = fmaxf(colp[0][t], colp[1][t]);
    const float scale = bn_w[0] / sqrtf(bn_v[0] + EPSV);
    const float bm = bn_m[0], bb = bn_b[0];
    partial = ((cmax - bm) * scale + bb) * fc_w[t] +
              ((rmax - bm) * scale + bb) * fc_w[HW + t];
  }
#pragma unroll
  for (int off = 1; off < 64; off <<= 1) partial += __shfl_xor(partial, off);
  if (lane == 0) wsum[wid] = partial;
  __syncthreads();
  if (t == 0) {
    const float sum = fc_b[0] + wsum[0] + wsum[1] + wsum[2] + wsum[3];
    const float logit = (sum - lbn_m[0]) * (lbn_w[0] / sqrtf(lbn_v[0] + EPSV)) + lbn_b[0];
    out[bid] = 1.f / (1.f + expf(-logit * 0.1f));
  }
}

// ---------------- naive f32 fallback (only if ws too small) ----------------
__global__ __launch_bounds__(256) void qaconv_naive(
    const float* __restrict__ gal, const float* __restrict__ prob,
    const float* __restrict__ bn_w, const float* __restrict__ bn_b,
    const float* __restrict__ bn_m, const float* __restrict__ bn_v,
    const float* __restrict__ fc_w, const float* __restrict__ fc_b,
    const float* __restrict__ lbn_w, const float* __restrict__ lbn_b,
    const float* __restrict__ lbn_m, const float* __restrict__ lbn_v,
    float* __restrict__ out) {
  __shared__ float prow[ND];
  __shared__ float rowmaxs[HW];
  __shared__ float colmaxs[HW];
  __shared__ float red[4];
  const int bid = blockIdx.x;
  const int g = bid >> 6, p = bid & 63;
  const int t = threadIdx.x, lane = t & 63, wid = t >> 6;
  const float* gp = gal + (size_t)g * ND * HW;
  const float* pp = prob + (size_t)p * ND * HW;
  float colmax = -3.4e38f;
  for (int y = 0; y < HW; ++y) {
    for (int k = t; k < ND; k += 256) prow[k] = pp[(size_t)k * HW + y];
    __syncthreads();
    float sv = -3.4e38f;
    if (t < HW) {
      sv = 0.f;
      for (int k = 0; k < ND; ++k) sv = fmaf(prow[k], gp[(size_t)k * HW + t], sv);
      colmax = fmaxf(colmax, sv);
    }
    float m = sv;
#pragma unroll
    for (int off = 1; off < 64; off <<= 1) m = fmaxf(m, __shfl_xor(m, off));
    if (lane == 0) red[wid] = m;
    __syncthreads();
    if (t == 0) rowmaxs[y] = fmaxf(fmaxf(red[0], red[1]), fmaxf(red[2], red[3]));
    __syncthreads();
  }
  if (t < HW) colmaxs[t] = colmax;
  __syncthreads();
  float partial = 0.f;
  for (int j = t; j < 2 * HW; j += 256) {
    const float v = (j < HW) ? colmaxs[j] : rowmaxs[j - HW];
    const float sc = (v - bn_m[0]) * (bn_w[0] / sqrtf(bn_v[0] + EPSV)) + bn_b[0];
    partial += sc * fc_w[j];
  }
#pragma unroll
  for (int off = 1; off < 64; off <<= 1) partial += __shfl_xor(partial, off);
  if (lane == 0) red[wid] = partial;
  __syncthreads();
  if (t == 0) {
    const float sum = fc_b[0] + red[0] + red[1] + red[2] + red[3];
    const float logit = (sum - lbn_m[0]) * (lbn_w[0] / sqrtf(lbn_v[0] + EPSV)) + lbn_b[0];
    out[bid] = 1.f / (1.f + expf(-logit * 0.1f));
  }
}

extern "C" void kernel_launch(void* const* d_in, const int* in_sizes, int n_in,
                              void* d_out, int out_size, void* d_ws, size_t ws_size,
                              hipStream_t stream) {
  const float* gal = (const float*)d_in[0];
  const float* prob = (const float*)d_in[1];
  const float* bn_w = (const float*)d_in[2];
  const float* bn_b = (const float*)d_in[3];
  const float* bn_m = (const float*)d_in[4];
  const float* bn_v = (const float*)d_in[5];
  const float* fc_w = (const float*)d_in[6];
  const float* fc_b = (const float*)d_in[7];
  const float* lbn_w = (const float*)d_in[8];
  const float* lbn_b = (const float*)d_in[9];
  const float* lbn_m = (const float*)d_in[10];
  const float* lbn_v = (const float*)d_in[11];
  float* out = (float*)d_out;

  const size_t probT4_elems = (size_t)NP * 98304;  // 6.29M halves
  const size_t galT4_elems = (size_t)NG * 98304;   // 3.15M halves
  const size_t ws_needed = (probT4_elems + galT4_elems) * sizeof(_Float16);
  if (ws_size >= ws_needed) {
    _Float16* probT4 = (_Float16*)d_ws;
    _Float16* galT4 = probT4 + probT4_elems;
    prep_frag<<<dim3(NP + NG, KS), dim3(256), 0, stream>>>(gal, prob, galT4, probT4);
    qaconv_main<<<dim3(NG * NP), dim3(256), 0, stream>>>(
        galT4, probT4, bn_w, bn_b, bn_m, bn_v, fc_w, fc_b, lbn_w, lbn_b, lbn_m, lbn_v, out);
  } else {
    qaconv_naive<<<dim3(NG * NP), dim3(256), 0, stream>>>(
        gal, prob, bn_w, bn_b, bn_m, bn_v, fc_w, fc_b, lbn_w, lbn_b, lbn_m, lbn_v, out);
  }
}